// Round 7
// baseline (230.778 us; speedup 1.0000x reference)
//
#include <hip/hip_runtime.h>
#include <hip/hip_bf16.h>
#include <math.h>

typedef __bf16 bf16;
typedef bf16 bf16x8 __attribute__((ext_vector_type(8)));
typedef float f32x4 __attribute__((ext_vector_type(4)));
typedef unsigned int u32;

#define EMB 1024
#define NH 16
#define DK 64
#define SEQ 2048
#define NB 2
#define NTOK (NB*SEQ)

// attention scale folded into Q at the QKV epilogue: 0.125 * log2(e)
#define QSCALE 0.18033688011112043f

#if defined(__has_builtin)
#if __has_builtin(__builtin_amdgcn_exp2f)
#define EXP2(x) __builtin_amdgcn_exp2f(x)
#else
#define EXP2(x) exp2f(x)
#endif
#else
#define EXP2(x) exp2f(x)
#endif

// async global->LDS, 16B per lane; lds dst = wave-uniform base + lane*16
__device__ __forceinline__ void gl_lds16(const void* g, void* l) {
    __builtin_amdgcn_global_load_lds(
        (const __attribute__((address_space(1))) u32*)g,
        (__attribute__((address_space(3))) u32*)l, 16, 0, 0);
}

// XOR-swizzled 64-wide LDS tile: elem(row,col) -> row*64 + ((col/8 ^ row%8)*8) + col%8
// Staging: lane (lrow=lane>>3, lc=lane&7) fetches global colblk (lc^lrow) so the
// wave-uniform-dst global_load_lds lands pre-swizzled. Rows must be 8-aligned.
#define SWZ(row, colblk) (((row)*64) + ((((colblk) ^ ((row)&7)))*8))

// P buffer: plain rows padded to 72 elems (144 B): affine addressing (all store
// offsets fold to immediates), b128 reads 16B-aligned & bank-balanced, writes <=2-way.
#define PSTR 72

// fp32 -> bf16 conversion for x / w_qkv / w_comb in one launch (y = segment)
__global__ __launch_bounds__(256) void convert3(
    const float* __restrict__ s0, const float* __restrict__ s1,
    const float* __restrict__ s2,
    bf16* __restrict__ d0, bf16* __restrict__ d1, bf16* __restrict__ d2)
{
    const float* src; bf16* dst; int n;
    switch (blockIdx.y) {
        case 0:  src = s0; dst = d0; n = NTOK*EMB;  break;
        case 1:  src = s1; dst = d1; n = 3*EMB*EMB; break;
        default: src = s2; dst = d2; n = EMB*EMB;   break;
    }
    int i = (blockIdx.x * 256 + threadIdx.x) * 4;
    if (i + 3 < n) {
        float4 v = *(const float4*)(src + i);
        dst[i+0] = (bf16)v.x; dst[i+1] = (bf16)v.y;
        dst[i+2] = (bf16)v.z; dst[i+3] = (bf16)v.w;
    }
}

// ---------------------------------------------------------------------------
// GEMM: D[m,n] = sum_k A[m,k] * B[n,k]   (row-major, K-contiguous, bf16)
// Tile BM x 128, BK=64, 4 waves; wave = (BM/2) x 64 via (BM/32)x4 16x16x32 MFMA
// MODE 0 (BM=128): scatter bf16 q*QSCALE, k into [b,h,s,d]; packed 8B vT[b,h,d,s]
// MODE 1: row-major fp32 [M x EMB]
// ---------------------------------------------------------------------------
template<int MODE, int BM>
__global__ __launch_bounds__(256) void gemm_bt(
    const bf16* __restrict__ Aa, const bf16* __restrict__ Bb,
    bf16* __restrict__ qb, bf16* __restrict__ kb, bf16* __restrict__ vtb,
    float* __restrict__ outc, int Kdim)
{
    constexpr int MI = BM / 32;
    __shared__ __align__(16) bf16 At[BM*64];
    __shared__ __align__(16) bf16 Bt[128*64];
    const int tid  = threadIdx.x;
    const int w    = tid >> 6, lane = tid & 63;
    const int quad = lane >> 4, l15 = lane & 15;
    const int wr   = w >> 1,   wc  = w & 1;
    const int m0 = blockIdx.y * BM, n0 = blockIdx.x * 128;
    const int lrow = lane >> 3;
    const int lswz = ((lane & 7) ^ lrow) * 8;       // swizzled global col offset

    f32x4 acc[MI][4] = {};

    for (int k0 = 0; k0 < Kdim; k0 += 64) {
        __syncthreads();
        for (int i = 0; i < MI; ++i) {
            int r = w*(BM/4) + i*8 + lrow;
            gl_lds16(Aa + (size_t)(m0 + r)*Kdim + k0 + lswz, At + (w*(BM/4) + i*8)*64);
        }
        for (int i = 0; i < 4; ++i) {
            int r = w*32 + i*8 + lrow;
            gl_lds16(Bb + (size_t)(n0 + r)*Kdim + k0 + lswz, Bt + (w*32 + i*8)*64);
        }
        __syncthreads();
        for (int kk = 0; kk < 2; ++kk) {
            bf16x8 a[MI], b[4];
            for (int i = 0; i < MI; ++i) {
                int row = wr*(BM/2) + i*16 + l15;
                a[i] = *(const bf16x8*)(At + SWZ(row, 4*kk + quad));
            }
            for (int j = 0; j < 4; ++j) {
                int row = wc*64 + j*16 + l15;
                b[j] = *(const bf16x8*)(Bt + SWZ(row, 4*kk + quad));
            }
            for (int i = 0; i < MI; ++i)
                for (int j = 0; j < 4; ++j)
                    acc[i][j] = __builtin_amdgcn_mfma_f32_16x16x32_bf16(a[i], b[j], acc[i][j], 0, 0, 0);
        }
    }

    for (int i = 0; i < MI; ++i) for (int j = 0; j < 4; ++j) {
        int rb  = m0 + wr*(BM/2) + i*16 + quad*4;
        int col = n0 + wc*64 + j*16 + l15;
        if (MODE == 0) {
            int c = col >> 10, h = (col >> 6) & 15, d = col & 63;
            int b_ = rb >> 11, s = rb & 2047;
            int bh = b_*NH + h;
            if (c == 2) {
                // lane holds 4 consecutive tokens at fixed d: pack 8B store to vT
                bf16 tmp[4] __attribute__((aligned(8)));
                for (int r = 0; r < 4; ++r) tmp[r] = (bf16)acc[i][j][r];
                *(ushort4*)(vtb + ((size_t)bh*DK + d)*SEQ + s) = *(ushort4*)tmp;
            } else if (c == 0) {
                for (int r = 0; r < 4; ++r)
                    qb[((size_t)bh*SEQ + s + r)*DK + d] = (bf16)(acc[i][j][r] * QSCALE);
            } else {
                for (int r = 0; r < 4; ++r)
                    kb[((size_t)bh*SEQ + s + r)*DK + d] = (bf16)acc[i][j][r];
            }
        } else {
            for (int r = 0; r < 4; ++r)
                outc[(size_t)(rb + r)*EMB + col] = acc[i][j][r];
        }
    }
}

// ---------------------------------------------------------------------------
// Flash attention: one block = one (b,h) x 64-row Q tile; 4 waves, each wave
// owns ONE 16-row strip (Q frags in registers). Grid = 1024 blocks = 4/CU =
// 16 waves/CU for latency hiding. No max-subtraction (scores O(1): exact;
// scale pre-folded into Q). K/V/Q tiles XOR-swizzled; P stride-72 affine.
// ---------------------------------------------------------------------------
__global__ __launch_bounds__(256) void attn_kernel(
    const bf16* __restrict__ q, const bf16* __restrict__ k,
    const bf16* __restrict__ vt, bf16* __restrict__ out)
{
    __shared__ __align__(16) bf16 QP[4*16*PSTR];   // 9 KB: Q tile (64-stride), then P (72-stride)
    __shared__ __align__(16) bf16 Kt[64*64];       // 8 KB
    __shared__ __align__(16) bf16 Vt[64*64];       // 8 KB

    const int tid  = threadIdx.x;
    const int w    = tid >> 6, lane = tid & 63;
    const int quad = lane >> 4, l15 = lane & 15;
    const int bh = blockIdx.y, qt = blockIdx.x;
    const int lrow = lane >> 3;
    const int lswz = ((lane & 7) ^ lrow) * 8;

    // stage Q tile (each wave stages exactly its own 16 rows, swizzled, 64-stride)
    for (int i = 0; i < 2; ++i) {
        int r = w*16 + i*8 + lrow;
        gl_lds16(q + ((size_t)bh*SEQ + qt*64 + r)*DK + lswz, QP + (w*16 + i*8)*64);
    }
    asm volatile("s_waitcnt vmcnt(0)" ::: "memory");

    bf16x8 qf[2];
    for (int kk = 0; kk < 2; ++kk)
        qf[kk] = *(const bf16x8*)(QP + SWZ(w*16 + l15, 4*kk + quad));

    bf16* Pw = QP + w * 16 * PSTR;                 // per-wave P region (16 x 72)

    f32x4 O[4] = {};
    float psum[4] = {};

    for (int kt = 0; kt < SEQ/64; ++kt) {
        __syncthreads();
        for (int i = 0; i < 2; ++i) {
            int r = w*16 + i*8 + lrow;
            gl_lds16(k  + ((size_t)bh*SEQ + kt*64 + r)*DK + lswz, Kt + (w*16 + i*8)*64);
            gl_lds16(vt + ((size_t)bh*DK + r)*SEQ + kt*64 + lswz, Vt + (w*16 + i*8)*64);
        }
        __syncthreads();

        f32x4 sc[4] = {};
        for (int kk = 0; kk < 2; ++kk)
            for (int j = 0; j < 4; ++j) {
                bf16x8 b = *(const bf16x8*)(Kt + SWZ(j*16 + l15, 4*kk + quad));
                sc[j] = __builtin_amdgcn_mfma_f32_16x16x32_bf16(qf[kk], b, sc[j], 0, 0, 0);
            }

        // scores already scaled (Q pre-multiplied): p = 2^s. Affine P stores —
        // base = quad*4*72 + l15 (loop-invariant), offsets fold to immediates.
        for (int j = 0; j < 4; ++j)
            for (int r = 0; r < 4; ++r) {
                float p = EXP2(sc[j][r]);
                psum[r] += p;
                Pw[(quad*4 + r)*PSTR + j*16 + l15] = (bf16)p;
            }

        asm volatile("s_waitcnt lgkmcnt(0)" ::: "memory");

        for (int kk = 0; kk < 2; ++kk) {
            bf16x8 a = *(const bf16x8*)(Pw + l15*PSTR + kk*32 + quad*8);
            for (int j = 0; j < 4; ++j) {
                bf16x8 vb = *(const bf16x8*)(Vt + SWZ(j*16 + l15, 4*kk + quad));
                O[j] = __builtin_amdgcn_mfma_f32_16x16x32_bf16(a, vb, O[j], 0, 0, 0);
            }
        }
    }

    // one cross-lane reduce for the row sums (rows spread over l15 lanes)
    for (int r = 0; r < 4; ++r) {
        float s = psum[r];
        for (int m = 1; m < 16; m <<= 1) s += __shfl_xor(s, m, 64);
        psum[r] = 1.f / s;
    }

    const int b_ = bh >> 4, h = bh & 15;
    for (int j = 0; j < 4; ++j)
        for (int r = 0; r < 4; ++r) {
            int t   = b_*SEQ + qt*64 + w*16 + quad*4 + r;
            int col = h*DK + j*16 + l15;
            out[(size_t)t*EMB + col] = (bf16)(O[j][r] * psum[r]);
        }
}

// ---------------------------------------------------------------------------
// Per-token (all fp32): r = x + comb + b_comb; x1 = LN1(r);
// f = sum cos(x1[:8])cos(theta)w1 + b1;  out = LN2(x1 + f)
// ---------------------------------------------------------------------------
__global__ __launch_bounds__(256) void ln_kernel(
    const float* __restrict__ x, const float* __restrict__ comb,
    const float* __restrict__ bcomb,
    const float* __restrict__ g1, const float* __restrict__ be1,
    const float* __restrict__ g2, const float* __restrict__ be2,
    const float* __restrict__ theta, const float* __restrict__ w1v,
    const float* __restrict__ b1v, float* __restrict__ out)
{
    const int t = blockIdx.x, tid = threadIdx.x;
    __shared__ float red[8];
    __shared__ float fp2[2];
    const int e0 = tid*4;

    float4 xv = *(const float4*)(x    + (size_t)t*EMB + e0);
    float4 cv = *(const float4*)(comb + (size_t)t*EMB + e0);
    float4 bv = *(const float4*)(bcomb + e0);
    float r[4] = { xv.x + cv.x + bv.x, xv.y + cv.y + bv.y,
                   xv.z + cv.z + bv.z, xv.w + cv.w + bv.w };

    float s = 0.f, ss = 0.f;
    for (int i = 0; i < 4; ++i) { s += r[i]; ss += r[i]*r[i]; }
    for (int m = 1; m < 64; m <<= 1) { s += __shfl_xor(s, m, 64); ss += __shfl_xor(ss, m, 64); }
    if ((tid & 63) == 0) { red[(tid>>6)*2] = s; red[(tid>>6)*2+1] = ss; }
    __syncthreads();
    s  = red[0] + red[2] + red[4] + red[6];
    ss = red[1] + red[3] + red[5] + red[7];
    float mean = s * (1.f/1024.f);
    float var  = ss * (1.f/1024.f) - mean*mean;
    float inv  = rsqrtf(var + 1e-5f);
    float x1[4];
    for (int i = 0; i < 4; ++i) {
        int e = e0 + i;
        x1[i] = (r[i] - mean)*inv*g1[e] + be1[e];
    }
    __syncthreads();
    if (e0 < 8) {
        float pf = 0.f;
        for (int i = 0; i < 4; ++i) {
            int e = e0 + i;
            pf += cosf(x1[i]) * cosf(theta[e]) * w1v[e];
        }
        fp2[tid] = pf;
    }
    __syncthreads();
    float f = fp2[0] + fp2[1] + b1v[0];

    float s2 = 0.f, ss2 = 0.f;
    for (int i = 0; i < 4; ++i) { float v2 = x1[i] + f; s2 += v2; ss2 += v2*v2; }
    for (int m = 1; m < 64; m <<= 1) { s2 += __shfl_xor(s2, m, 64); ss2 += __shfl_xor(ss2, m, 64); }
    if ((tid & 63) == 0) { red[(tid>>6)*2] = s2; red[(tid>>6)*2+1] = ss2; }
    __syncthreads();
    s2  = red[0] + red[2] + red[4] + red[6];
    ss2 = red[1] + red[3] + red[5] + red[7];
    float mean2 = s2 * (1.f/1024.f);
    float var2  = ss2 * (1.f/1024.f) - mean2*mean2;
    float inv2  = rsqrtf(var2 + 1e-5f);
    float4 ov;
    ov.x = ((x1[0] + f) - mean2)*inv2*g2[e0+0] + be2[e0+0];
    ov.y = ((x1[1] + f) - mean2)*inv2*g2[e0+1] + be2[e0+1];
    ov.z = ((x1[2] + f) - mean2)*inv2*g2[e0+2] + be2[e0+2];
    ov.w = ((x1[3] + f) - mean2)*inv2*g2[e0+3] + be2[e0+3];
    *(float4*)(out + (size_t)t*EMB + e0) = ov;
}

extern "C" void kernel_launch(void* const* d_in, const int* in_sizes, int n_in,
                              void* d_out, int out_size, void* d_ws, size_t ws_size,
                              hipStream_t stream)
{
    const float* x      = (const float*)d_in[0];
    const float* w_qkv  = (const float*)d_in[1];
    const float* w_comb = (const float*)d_in[2];
    const float* b_comb = (const float*)d_in[3];
    const float* g1     = (const float*)d_in[4];
    const float* be1    = (const float*)d_in[5];
    const float* g2     = (const float*)d_in[6];
    const float* be2    = (const float*)d_in[7];
    const float* theta  = (const float*)d_in[8];
    const float* w1v    = (const float*)d_in[9];
    const float* b1v    = (const float*)d_in[10];
    float* out = (float*)d_out;

    char* ws = (char*)d_ws;
    bf16*  xb     = (bf16*)(ws);                    // [ 0,  8) MB
    bf16*  wqkvb  = (bf16*)(ws + ( 8u<<20));        // [ 8, 14) MB
    bf16*  wcombb = (bf16*)(ws + (14u<<20));        // [14, 16) MB
    bf16*  qb     = (bf16*)(ws + (16u<<20));        // [16, 24) MB
    bf16*  kb     = (bf16*)(ws + (24u<<20));        // [24, 32) MB
    bf16*  vtb    = (bf16*)(ws + (32u<<20));        // [32, 40) MB
    bf16*  attn   = (bf16*)(ws + (40u<<20));        // [40, 48) MB
    float* comb   = (float*)(ws + (16u<<20));       // [16, 32) MB (aliases dead q,k)

    convert3<<<dim3(4096, 3), 256, 0, stream>>>(x, w_qkv, w_comb, xb, wqkvb, wcombb);

    gemm_bt<0,128><<<dim3(3*EMB/128, NTOK/128), 256, 0, stream>>>(
        xb, wqkvb, qb, kb, vtb, nullptr, EMB);
    attn_kernel<<<dim3(SEQ/64, NB*NH), 256, 0, stream>>>(qb, kb, vtb, attn);
    gemm_bt<1,64><<<dim3(EMB/128, NTOK/64), 256, 0, stream>>>(
        attn, wcombb, nullptr, nullptr, nullptr, comb, EMB);
    ln_kernel<<<NTOK, 256, 0, stream>>>(x, comb, b_comb, g1, be1, g2, be2,
                                        theta, w1v, b1v, out);
}

// Round 8
// 215.914 us; speedup vs baseline: 1.0688x; 1.0688x over previous
//
#include <hip/hip_runtime.h>
#include <hip/hip_bf16.h>
#include <math.h>

typedef __bf16 bf16;
typedef bf16 bf16x8 __attribute__((ext_vector_type(8)));
typedef float f32x4 __attribute__((ext_vector_type(4)));
typedef unsigned int u32;

#define EMB 1024
#define NH 16
#define DK 64
#define SEQ 2048
#define NB 2
#define NTOK (NB*SEQ)

// attention scale folded into Q at the QKV epilogue: 0.125 * log2(e)
#define QSCALE 0.18033688011112043f

#if defined(__has_builtin)
#if __has_builtin(__builtin_amdgcn_exp2f)
#define EXP2(x) __builtin_amdgcn_exp2f(x)
#else
#define EXP2(x) exp2f(x)
#endif
#else
#define EXP2(x) exp2f(x)
#endif

// async global->LDS, 16B per lane; lds dst = wave-uniform base + lane*16
__device__ __forceinline__ void gl_lds16(const void* g, void* l) {
    __builtin_amdgcn_global_load_lds(
        (const __attribute__((address_space(1))) u32*)g,
        (__attribute__((address_space(3))) u32*)l, 16, 0, 0);
}

// XOR-swizzled 64-wide LDS tile: elem(row,col) -> row*64 + ((col/8 ^ row%8)*8) + col%8
// Staging: lane (lrow=lane>>3, lc=lane&7) fetches global colblk (lc^lrow) so the
// wave-uniform-dst global_load_lds lands pre-swizzled. Rows must be 8-aligned.
#define SWZ(row, colblk) (((row)*64) + ((((colblk) ^ ((row)&7)))*8))

// P buffer: plain rows padded to 72 elems (144 B): affine addressing (all store
// offsets fold to immediates), b128 reads 16B-aligned & bank-balanced, writes <=2-way.
#define PSTR 72

// fp32 -> bf16 conversion for x / w_qkv / w_comb in one launch (y = segment)
__global__ __launch_bounds__(256) void convert3(
    const float* __restrict__ s0, const float* __restrict__ s1,
    const float* __restrict__ s2,
    bf16* __restrict__ d0, bf16* __restrict__ d1, bf16* __restrict__ d2)
{
    const float* src; bf16* dst; int n;
    switch (blockIdx.y) {
        case 0:  src = s0; dst = d0; n = NTOK*EMB;  break;
        case 1:  src = s1; dst = d1; n = 3*EMB*EMB; break;
        default: src = s2; dst = d2; n = EMB*EMB;   break;
    }
    int i = (blockIdx.x * 256 + threadIdx.x) * 4;
    if (i + 3 < n) {
        float4 v = *(const float4*)(src + i);
        dst[i+0] = (bf16)v.x; dst[i+1] = (bf16)v.y;
        dst[i+2] = (bf16)v.z; dst[i+3] = (bf16)v.w;
    }
}

// ---------------------------------------------------------------------------
// GEMM: D[m,n] = sum_k A[m,k] * B[n,k]   (row-major, K-contiguous, bf16)
// Tile BM x 128, BK=64, 4 waves; wave = (BM/2) x 64 via (BM/32)x4 16x16x32 MFMA
// MODE 0 (BM=128): scatter bf16 q*QSCALE, k into [b,h,s,d]; packed 8B vT[b,h,d,s]
// MODE 1: row-major fp32 [M x EMB]
// ---------------------------------------------------------------------------
template<int MODE, int BM>
__global__ __launch_bounds__(256) void gemm_bt(
    const bf16* __restrict__ Aa, const bf16* __restrict__ Bb,
    bf16* __restrict__ qb, bf16* __restrict__ kb, bf16* __restrict__ vtb,
    float* __restrict__ outc, int Kdim)
{
    constexpr int MI = BM / 32;
    __shared__ __align__(16) bf16 At[BM*64];
    __shared__ __align__(16) bf16 Bt[128*64];
    const int tid  = threadIdx.x;
    const int w    = tid >> 6, lane = tid & 63;
    const int quad = lane >> 4, l15 = lane & 15;
    const int wr   = w >> 1,   wc  = w & 1;
    const int m0 = blockIdx.y * BM, n0 = blockIdx.x * 128;
    const int lrow = lane >> 3;
    const int lswz = ((lane & 7) ^ lrow) * 8;       // swizzled global col offset

    f32x4 acc[MI][4] = {};

    for (int k0 = 0; k0 < Kdim; k0 += 64) {
        __syncthreads();
        for (int i = 0; i < MI; ++i) {
            int r = w*(BM/4) + i*8 + lrow;
            gl_lds16(Aa + (size_t)(m0 + r)*Kdim + k0 + lswz, At + (w*(BM/4) + i*8)*64);
        }
        for (int i = 0; i < 4; ++i) {
            int r = w*32 + i*8 + lrow;
            gl_lds16(Bb + (size_t)(n0 + r)*Kdim + k0 + lswz, Bt + (w*32 + i*8)*64);
        }
        __syncthreads();
        for (int kk = 0; kk < 2; ++kk) {
            bf16x8 a[MI], b[4];
            for (int i = 0; i < MI; ++i) {
                int row = wr*(BM/2) + i*16 + l15;
                a[i] = *(const bf16x8*)(At + SWZ(row, 4*kk + quad));
            }
            for (int j = 0; j < 4; ++j) {
                int row = wc*64 + j*16 + l15;
                b[j] = *(const bf16x8*)(Bt + SWZ(row, 4*kk + quad));
            }
            for (int i = 0; i < MI; ++i)
                for (int j = 0; j < 4; ++j)
                    acc[i][j] = __builtin_amdgcn_mfma_f32_16x16x32_bf16(a[i], b[j], acc[i][j], 0, 0, 0);
        }
    }

    for (int i = 0; i < MI; ++i) for (int j = 0; j < 4; ++j) {
        int rb  = m0 + wr*(BM/2) + i*16 + quad*4;
        int col = n0 + wc*64 + j*16 + l15;
        if (MODE == 0) {
            int c = col >> 10, h = (col >> 6) & 15, d = col & 63;
            int b_ = rb >> 11, s = rb & 2047;
            int bh = b_*NH + h;
            if (c == 2) {
                // lane holds 4 consecutive tokens at fixed d: pack 8B store to vT
                bf16 tmp[4] __attribute__((aligned(8)));
                for (int r = 0; r < 4; ++r) tmp[r] = (bf16)acc[i][j][r];
                *(ushort4*)(vtb + ((size_t)bh*DK + d)*SEQ + s) = *(ushort4*)tmp;
            } else if (c == 0) {
                for (int r = 0; r < 4; ++r)
                    qb[((size_t)bh*SEQ + s + r)*DK + d] = (bf16)(acc[i][j][r] * QSCALE);
            } else {
                for (int r = 0; r < 4; ++r)
                    kb[((size_t)bh*SEQ + s + r)*DK + d] = (bf16)acc[i][j][r];
            }
        } else {
            for (int r = 0; r < 4; ++r)
                outc[(size_t)(rb + r)*EMB + col] = acc[i][j][r];
        }
    }
}

// ---------------------------------------------------------------------------
// Flash attention: one block = one (b,h) x 128-row Q tile; 4 waves, each wave
// owns 32 Q rows (2x16 strips), Q frags in registers. K/V double-buffered in
// DISTINCT static LDS arrays (so AA lets prefetch stay in flight across the
// other buffer's ds_reads); kt unrolled x2, ONE barrier per kt. Prefetch is
// issued right after the barrier and drains at the NEXT barrier — a full
// compute phase of overlap. No max-subtraction (scores O(1): exact; scale
// pre-folded into Q). Tiles XOR-swizzled; P stride-72 affine.
// ---------------------------------------------------------------------------
__global__ __launch_bounds__(256) void attn_kernel(
    const bf16* __restrict__ q, const bf16* __restrict__ k,
    const bf16* __restrict__ vt, bf16* __restrict__ out)
{
    __shared__ __align__(16) bf16 QP[4*32*PSTR];   // 18 KB: Q tile (64-stride), then P (72-stride)
    __shared__ __align__(16) bf16 Kt0[64*64];      // 8 KB each
    __shared__ __align__(16) bf16 Kt1[64*64];
    __shared__ __align__(16) bf16 Vt0[64*64];
    __shared__ __align__(16) bf16 Vt1[64*64];

    const int tid  = threadIdx.x;
    const int w    = tid >> 6, lane = tid & 63;
    const int quad = lane >> 4, l15 = lane & 15;
    const int bh = blockIdx.y, qt = blockIdx.x;
    const int lrow = lane >> 3;
    const int lswz = ((lane & 7) ^ lrow) * 8;

    // stage Q tile (each wave stages exactly its own 32 rows, swizzled, 64-stride)
    for (int i = 0; i < 4; ++i) {
        int r = w*32 + i*8 + lrow;
        gl_lds16(q + ((size_t)bh*SEQ + qt*128 + r)*DK + lswz, QP + (w*32 + i*8)*64);
    }
    asm volatile("s_waitcnt vmcnt(0)" ::: "memory");

    bf16x8 qf[2][2];
    for (int rt = 0; rt < 2; ++rt)
        for (int kk = 0; kk < 2; ++kk)
            qf[rt][kk] = *(const bf16x8*)(QP + SWZ(w*32 + rt*16 + l15, 4*kk + quad));

    bf16* Pw = QP + w * 32 * PSTR;                 // per-wave P region (32 x 72)

    f32x4 O[2][4] = {};
    float psum[2][4] = {};

    auto stage_kv = [&](int kt, bf16* Kb, bf16* Vb) {
        for (int i = 0; i < 2; ++i) {
            int r = w*16 + i*8 + lrow;
            gl_lds16(k  + ((size_t)bh*SEQ + kt*64 + r)*DK + lswz, Kb + (w*16 + i*8)*64);
            gl_lds16(vt + ((size_t)bh*DK + r)*SEQ + kt*64 + lswz, Vb + (w*16 + i*8)*64);
        }
    };

    auto compute = [&](const bf16* Kb, const bf16* Vb) {
        f32x4 sc[2][4] = {};
        for (int kk = 0; kk < 2; ++kk)
            for (int j = 0; j < 4; ++j) {
                bf16x8 b = *(const bf16x8*)(Kb + SWZ(j*16 + l15, 4*kk + quad));
                for (int rt = 0; rt < 2; ++rt)
                    sc[rt][j] = __builtin_amdgcn_mfma_f32_16x16x32_bf16(qf[rt][kk], b, sc[rt][j], 0, 0, 0);
            }
        // scores pre-scaled (Q folded): p = 2^s. Affine P stores, imm offsets.
        for (int rt = 0; rt < 2; ++rt)
            for (int j = 0; j < 4; ++j)
                for (int r = 0; r < 4; ++r) {
                    float p = EXP2(sc[rt][j][r]);
                    psum[rt][r] += p;
                    Pw[(rt*16 + quad*4 + r)*PSTR + j*16 + l15] = (bf16)p;
                }
        asm volatile("s_waitcnt lgkmcnt(0)" ::: "memory");
        for (int kk = 0; kk < 2; ++kk) {
            bf16x8 vb[4];
            for (int j = 0; j < 4; ++j)
                vb[j] = *(const bf16x8*)(Vb + SWZ(j*16 + l15, 4*kk + quad));
            for (int rt = 0; rt < 2; ++rt) {
                bf16x8 a = *(const bf16x8*)(Pw + (rt*16 + l15)*PSTR + kk*32 + quad*8);
                for (int j = 0; j < 4; ++j)
                    O[rt][j] = __builtin_amdgcn_mfma_f32_16x16x32_bf16(a, vb[j], O[rt][j], 0, 0, 0);
            }
        }
    };

    stage_kv(0, Kt0, Vt0);
    for (int kt2 = 0; kt2 < SEQ/128; ++kt2) {
        __syncthreads();                            // drains KV(2*kt2) -> buf0
        stage_kv(2*kt2 + 1, Kt1, Vt1);              // in flight across compute
        compute(Kt0, Vt0);
        __syncthreads();                            // drains KV(2*kt2+1) -> buf1
        if (kt2 + 1 < SEQ/128)
            stage_kv(2*kt2 + 2, Kt0, Vt0);
        compute(Kt1, Vt1);
    }

    // one cross-lane reduce for the row sums (rows spread over l15 lanes)
    for (int rt = 0; rt < 2; ++rt)
        for (int r = 0; r < 4; ++r) {
            float s = psum[rt][r];
            for (int m = 1; m < 16; m <<= 1) s += __shfl_xor(s, m, 64);
            psum[rt][r] = 1.f / s;
        }

    const int b_ = bh >> 4, h = bh & 15;
    for (int rt = 0; rt < 2; ++rt)
        for (int j = 0; j < 4; ++j)
            for (int r = 0; r < 4; ++r) {
                int t   = b_*SEQ + qt*128 + w*32 + rt*16 + quad*4 + r;
                int col = h*DK + j*16 + l15;
                out[(size_t)t*EMB + col] = (bf16)(O[rt][j][r] * psum[rt][r]);
            }
}

// ---------------------------------------------------------------------------
// Per-token (all fp32): r = x + comb + b_comb; x1 = LN1(r);
// f = sum cos(x1[:8])cos(theta)w1 + b1;  out = LN2(x1 + f)
// ---------------------------------------------------------------------------
__global__ __launch_bounds__(256) void ln_kernel(
    const float* __restrict__ x, const float* __restrict__ comb,
    const float* __restrict__ bcomb,
    const float* __restrict__ g1, const float* __restrict__ be1,
    const float* __restrict__ g2, const float* __restrict__ be2,
    const float* __restrict__ theta, const float* __restrict__ w1v,
    const float* __restrict__ b1v, float* __restrict__ out)
{
    const int t = blockIdx.x, tid = threadIdx.x;
    __shared__ float red[8];
    __shared__ float fp2[2];
    const int e0 = tid*4;

    float4 xv = *(const float4*)(x    + (size_t)t*EMB + e0);
    float4 cv = *(const float4*)(comb + (size_t)t*EMB + e0);
    float4 bv = *(const float4*)(bcomb + e0);
    float r[4] = { xv.x + cv.x + bv.x, xv.y + cv.y + bv.y,
                   xv.z + cv.z + bv.z, xv.w + cv.w + bv.w };

    float s = 0.f, ss = 0.f;
    for (int i = 0; i < 4; ++i) { s += r[i]; ss += r[i]*r[i]; }
    for (int m = 1; m < 64; m <<= 1) { s += __shfl_xor(s, m, 64); ss += __shfl_xor(ss, m, 64); }
    if ((tid & 63) == 0) { red[(tid>>6)*2] = s; red[(tid>>6)*2+1] = ss; }
    __syncthreads();
    s  = red[0] + red[2] + red[4] + red[6];
    ss = red[1] + red[3] + red[5] + red[7];
    float mean = s * (1.f/1024.f);
    float var  = ss * (1.f/1024.f) - mean*mean;
    float inv  = rsqrtf(var + 1e-5f);
    float x1[4];
    for (int i = 0; i < 4; ++i) {
        int e = e0 + i;
        x1[i] = (r[i] - mean)*inv*g1[e] + be1[e];
    }
    __syncthreads();
    if (e0 < 8) {
        float pf = 0.f;
        for (int i = 0; i < 4; ++i) {
            int e = e0 + i;
            pf += cosf(x1[i]) * cosf(theta[e]) * w1v[e];
        }
        fp2[tid] = pf;
    }
    __syncthreads();
    float f = fp2[0] + fp2[1] + b1v[0];

    float s2 = 0.f, ss2 = 0.f;
    for (int i = 0; i < 4; ++i) { float v2 = x1[i] + f; s2 += v2; ss2 += v2*v2; }
    for (int m = 1; m < 64; m <<= 1) { s2 += __shfl_xor(s2, m, 64); ss2 += __shfl_xor(ss2, m, 64); }
    if ((tid & 63) == 0) { red[(tid>>6)*2] = s2; red[(tid>>6)*2+1] = ss2; }
    __syncthreads();
    s2  = red[0] + red[2] + red[4] + red[6];
    ss2 = red[1] + red[3] + red[5] + red[7];
    float mean2 = s2 * (1.f/1024.f);
    float var2  = ss2 * (1.f/1024.f) - mean2*mean2;
    float inv2  = rsqrtf(var2 + 1e-5f);
    float4 ov;
    ov.x = ((x1[0] + f) - mean2)*inv2*g2[e0+0] + be2[e0+0];
    ov.y = ((x1[1] + f) - mean2)*inv2*g2[e0+1] + be2[e0+1];
    ov.z = ((x1[2] + f) - mean2)*inv2*g2[e0+2] + be2[e0+2];
    ov.w = ((x1[3] + f) - mean2)*inv2*g2[e0+3] + be2[e0+3];
    *(float4*)(out + (size_t)t*EMB + e0) = ov;
}

extern "C" void kernel_launch(void* const* d_in, const int* in_sizes, int n_in,
                              void* d_out, int out_size, void* d_ws, size_t ws_size,
                              hipStream_t stream)
{
    const float* x      = (const float*)d_in[0];
    const float* w_qkv  = (const float*)d_in[1];
    const float* w_comb = (const float*)d_in[2];
    const float* b_comb = (const float*)d_in[3];
    const float* g1     = (const float*)d_in[4];
    const float* be1    = (const float*)d_in[5];
    const float* g2     = (const float*)d_in[6];
    const float* be2    = (const float*)d_in[7];
    const float* theta  = (const float*)d_in[8];
    const float* w1v    = (const float*)d_in[9];
    const float* b1v    = (const float*)d_in[10];
    float* out = (float*)d_out;

    char* ws = (char*)d_ws;
    bf16*  xb     = (bf16*)(ws);                    // [ 0,  8) MB
    bf16*  wqkvb  = (bf16*)(ws + ( 8u<<20));        // [ 8, 14) MB
    bf16*  wcombb = (bf16*)(ws + (14u<<20));        // [14, 16) MB
    bf16*  qb     = (bf16*)(ws + (16u<<20));        // [16, 24) MB
    bf16*  kb     = (bf16*)(ws + (24u<<20));        // [24, 32) MB
    bf16*  vtb    = (bf16*)(ws + (32u<<20));        // [32, 40) MB
    bf16*  attn   = (bf16*)(ws + (40u<<20));        // [40, 48) MB
    float* comb   = (float*)(ws + (16u<<20));       // [16, 32) MB (aliases dead q,k)

    convert3<<<dim3(4096, 3), 256, 0, stream>>>(x, w_qkv, w_comb, xb, wqkvb, wcombb);

    gemm_bt<0,128><<<dim3(3*EMB/128, NTOK/128), 256, 0, stream>>>(
        xb, wqkvb, qb, kb, vtb, nullptr, EMB);
    attn_kernel<<<dim3(SEQ/128, NB*NH), 256, 0, stream>>>(qb, kb, vtb, attn);
    gemm_bt<1,64><<<dim3(EMB/128, NTOK/64), 256, 0, stream>>>(
        attn, wcombb, nullptr, nullptr, nullptr, comb, EMB);
    ln_kernel<<<NTOK, 256, 0, stream>>>(x, comb, b_comb, g1, be1, g2, be2,
                                        theta, w1v, b1v, out);
}